// Round 7
// baseline (408.335 us; speedup 1.0000x reference)
//
#include <hip/hip_runtime.h>
#include <hip/hip_bf16.h>
#include <math.h>

#define B_ 2
#define H_ 8
#define N_ 2048
#define D_ 64
#define BH_ 16
#define NT_ (N_/64)
#define LS 72
#define LSW (LS/2)
#define ASTR 68   // Acc row stride in floats (16B-aligned rows; [0..63]=O, [64]=rowsum)

typedef __attribute__((ext_vector_type(8))) short short8;
typedef __attribute__((ext_vector_type(4))) float float4v;

__device__ __forceinline__ unsigned packbf2(float a, float b){
  __hip_bfloat162 h = __float22bfloat162_rn(make_float2(a, b));
  return *(unsigned*)&h;
}
__device__ __forceinline__ void split2(float a, float b, unsigned& hi, unsigned& lo){
  hi = packbf2(a, b);
  float ha = __uint_as_float(hi << 16);
  float hb = __uint_as_float(hi & 0xFFFF0000u);
  lo = packbf2(a - ha, b - hb);
}
__device__ __forceinline__ void load_split8(const float* p, short8& hi8, short8& lo8){
  float4v v0 = *(const float4v*)p;
  float4v v1 = *(const float4v*)(p + 4);
  unsigned h0,h1,h2,h3,l0,l1,l2,l3;
  split2(v0.x, v0.y, h0, l0);
  split2(v0.z, v0.w, h1, l1);
  split2(v1.x, v1.y, h2, l2);
  split2(v1.z, v1.w, h3, l3);
  unsigned ph[4] = {h0,h1,h2,h3};
  unsigned pl[4] = {l0,l1,l2,l3};
  hi8 = *(short8*)ph;
  lo8 = *(short8*)pl;
}
__device__ __forceinline__ float acos_poly(float z){
  float p = 4.2163199048e-2f;
  p = __builtin_fmaf(p, z, 2.4181311049e-2f);
  p = __builtin_fmaf(p, z, 4.5470025998e-2f);
  p = __builtin_fmaf(p, z, 7.4953002686e-2f);
  p = __builtin_fmaf(p, z, 1.6666752422e-1f);
  return p;
}
__device__ __forceinline__ float score_fn(float qk, float masked){
  const float LO = -1.0f + 1e-7f;
  const float HI =  1.0f - 1e-7f;
  float x  = fminf(fmaxf(qk, LO), HI);
  float ax = fabsf(x);
  bool big = ax > 0.5f;
  float z  = big ? (0.5f*(1.0f - ax)) : (x*x);
  float s  = big ? __builtin_amdgcn_sqrtf(z) : x;
  float p  = acos_poly(z);
  float r  = __builtin_fmaf(s*z, p, s);
  float g_big   = (x >= 0.0f) ? (2.0f*r) : __builtin_fmaf(-2.0f, r, 3.14159265358979f);
  float g_small = 1.57079632679490f - r;
  float g = big ? g_big : g_small;
  g = (masked != 0.0f) ? 10000.0f : g;
  float w1 = 1.0f + g;
  float w2 = w1*w1;
  float w4 = w2*w2;
  float w5 = w4*w1;
  return __builtin_amdgcn_rcpf(w5);
}

// k1 (STORE=true): scores -> S bf16, col sums atomically into ncw.
// k1 (STORE=false): full column sums, ncw = n_c^-0.5 directly (fallback pass1).
template<bool STORE>
__global__ __launch_bounds__(256) void k1_score(
    const float* __restrict__ Q, const float* __restrict__ K,
    const int* __restrict__ mask, float* __restrict__ ncw,
    unsigned short* __restrict__ S)
{
  __shared__ unsigned short Qhi[64*LS], Qlo[64*LS];
  __shared__ float msk[64];
  __shared__ float red[64*4];

  const int kt = blockIdx.x, bh = blockIdx.y, rz = blockIdx.z;
  const int nz = gridDim.z;
  const int tid = threadIdx.x;
  const int wv = tid>>6, lane = tid&63, quad = lane>>4, l15 = lane&15;

  const float* Qg = Q + (size_t)bh*N_*D_;
  const float* Kg = K + (size_t)bh*N_*D_;

  short8 khi[4][2], klo[4][2];
  #pragma unroll
  for (int s=0;s<4;++s){
    const float* kp = Kg + (size_t)(kt*64 + s*16 + l15)*D_ + quad*8;
    load_split8(kp,      khi[s][0], klo[s][0]);
    load_split8(kp + 32, khi[s][1], klo[s][1]);
  }
  if (tid < 64)
    msk[tid] = (mask[(bh>>3)*N_ + kt*64 + tid] == 0) ? 1.f : 0.f;

  float cs[4][4];
  #pragma unroll
  for (int s=0;s<4;++s)
    #pragma unroll
    for (int i=0;i<4;++i) cs[s][i] = 0.f;

  const int iters = NT_/nz;
  for (int rti=0; rti<iters; ++rti){
    const int rt = rz*iters + rti;
    __syncthreads();
    #pragma unroll
    for (int it=0; it<4; ++it){
      int idx = tid + it*256;
      int r = idx>>4, d4 = (idx&15)<<2;
      const float4v v = *(const float4v*)(Qg + (size_t)(rt*64 + r)*D_ + d4);
      unsigned h0,l0,h1,l1;
      split2(v.x, v.y, h0, l0);
      split2(v.z, v.w, h1, l1);
      unsigned* QhiW = (unsigned*)Qhi; unsigned* QloW = (unsigned*)Qlo;
      int base = r*LSW + (d4>>1);
      QhiW[base] = h0; QhiW[base+1] = h1;
      QloW[base] = l0; QloW[base+1] = l1;
    }
    __syncthreads();

    short8 bhi[2], blo[2];
    #pragma unroll
    for (int cc=0; cc<2; ++cc){
      bhi[cc] = *(const short8*)&Qhi[(wv*16+l15)*LS + cc*32 + quad*8];
      blo[cc] = *(const short8*)&Qlo[(wv*16+l15)*LS + cc*32 + quad*8];
    }
    const size_t nrow = (size_t)(bh*NT_ + kt)*N_ + (size_t)rt*64 + wv*16 + l15;
    #pragma unroll
    for (int s=0;s<4;++s){
      float4v c = {0.f,0.f,0.f,0.f};
      #pragma unroll
      for (int cc=0; cc<2; ++cc){
        c = __builtin_amdgcn_mfma_f32_16x16x32_bf16(khi[s][cc], bhi[cc], c, 0,0,0);
        c = __builtin_amdgcn_mfma_f32_16x16x32_bf16(khi[s][cc], blo[cc], c, 0,0,0);
        c = __builtin_amdgcn_mfma_f32_16x16x32_bf16(klo[s][cc], bhi[cc], c, 0,0,0);
      }
      int kl = s*16 + quad*4;
      float sc0 = score_fn(c[0], msk[kl+0]);
      float sc1 = score_fn(c[1], msk[kl+1]);
      float sc2 = score_fn(c[2], msk[kl+2]);
      float sc3 = score_fn(c[3], msk[kl+3]);
      cs[s][0]+=sc0; cs[s][1]+=sc1; cs[s][2]+=sc2; cs[s][3]+=sc3;
      if (STORE){
        uint2 pk;
        pk.x = packbf2(sc0, sc1);
        pk.y = packbf2(sc2, sc3);
        *(uint2*)&S[nrow*64 + kl] = pk;
      }
    }
  }

  #pragma unroll
  for (int s=0;s<4;++s)
    #pragma unroll
    for (int i=0;i<4;++i){
      float v2 = cs[s][i];
      v2 += __shfl_xor(v2, 1);
      v2 += __shfl_xor(v2, 2);
      v2 += __shfl_xor(v2, 4);
      v2 += __shfl_xor(v2, 8);
      cs[s][i] = v2;
    }
  if (l15 == 0){
    #pragma unroll
    for (int s=0;s<4;++s)
      #pragma unroll
      for (int i=0;i<4;++i)
        red[(s*16 + quad*4 + i)*4 + wv] = cs[s][i];
  }
  __syncthreads();
  if (tid < 64){
    float t = red[tid*4+0] + red[tid*4+1] + red[tid*4+2] + red[tid*4+3];
    if (STORE) atomicAdd(&ncw[bh*N_ + kt*64 + tid], t);
    else       ncw[bh*N_ + kt*64 + tid] = 1.0f / sqrtf(t);
  }
}

__global__ __launch_bounds__(256) void k2_w(const float* __restrict__ nc,
                                            float* __restrict__ w){
  int i = blockIdx.x*256 + threadIdx.x;
  w[i] = 1.0f / sqrtf(fmaxf(nc[i], 1e-30f));
}

// k3: P·(w*V) from stored S. SPLIT: z-blocks cover key subranges, fp32-atomic
// partial accumulation into Acc[row][0..63]+rowsum[64]. !SPLIT: direct out.
template<bool SPLIT>
__global__ __launch_bounds__(256) void k3_pv(
    const float* __restrict__ V, const unsigned short* __restrict__ S,
    const float* __restrict__ w, float* __restrict__ Acc,
    float* __restrict__ out)
{
  __shared__ unsigned short Vt[80*LS];   // 0..63: (w*V)^T[d][m]; 64: w; 65..79: 0

  const int rt = blockIdx.x, bh = blockIdx.y;
  const int tid = threadIdx.x;
  const int wv = tid>>6, lane = tid&63, quad = lane>>4, l15 = lane&15;

  const float* Vg = V + (size_t)bh*N_*D_;
  const float* wg = w + (size_t)bh*N_;

  {
    unsigned* VtW = (unsigned*)&Vt[64*LS];
    for (int z = tid; z < 16*LSW; z += 256) VtW[z] = 0u;
  }

  float4v acc[4];
  #pragma unroll
  for (int i=0;i<4;++i) acc[i] = (float4v){0.f,0.f,0.f,0.f};
  float4v c5 = {0.f,0.f,0.f,0.f};

  const int nz = SPLIT ? gridDim.z : 1;
  const int iters = NT_/nz;
  const int kt0 = SPLIT ? (blockIdx.z*iters) : 0;

  for (int ki=0; ki<iters; ++ki){
    const int kt = kt0 + ki;
    __syncthreads();
    #pragma unroll
    for (int it=0; it<2; ++it){
      int u = tid + it*256;
      int kp = u & 31;
      int d4 = (u>>5)<<2;
      int m0 = kt*64 + kp*2;
      float wa = wg[m0], wb = wg[m0+1];
      const float* vp = Vg + (size_t)m0*D_ + d4;
      float4v a0 = *(const float4v*)vp;
      float4v a1 = *(const float4v*)(vp + D_);
      unsigned* VtW = (unsigned*)Vt;
      VtW[(d4+0)*LSW + kp] = packbf2(a0.x*wa, a1.x*wb);
      VtW[(d4+1)*LSW + kp] = packbf2(a0.y*wa, a1.y*wb);
      VtW[(d4+2)*LSW + kp] = packbf2(a0.z*wa, a1.z*wb);
      VtW[(d4+3)*LSW + kp] = packbf2(a0.w*wa, a1.w*wb);
    }
    if (tid < 32){
      int m0 = kt*64 + tid*2;
      ((unsigned*)Vt)[64*LSW + tid] = packbf2(wg[m0], wg[m0+1]);
    }
    __syncthreads();

    const size_t base = ((size_t)(bh*NT_ + kt)*N_ + (size_t)rt*64 + wv*16 + l15)*64;
    short8 pf0 = *(const short8*)&S[base +  0 + quad*8];
    short8 pf1 = *(const short8*)&S[base + 32 + quad*8];

    #pragma unroll
    for (int s2=0;s2<4;++s2){
      const short8 a0 = *(const short8*)&Vt[(s2*16+l15)*LS +  0 + quad*8];
      const short8 a1 = *(const short8*)&Vt[(s2*16+l15)*LS + 32 + quad*8];
      acc[s2] = __builtin_amdgcn_mfma_f32_16x16x32_bf16(a0, pf0, acc[s2], 0,0,0);
      acc[s2] = __builtin_amdgcn_mfma_f32_16x16x32_bf16(a1, pf1, acc[s2], 0,0,0);
    }
    {
      const short8 a0 = *(const short8*)&Vt[(64+l15)*LS +  0 + quad*8];
      const short8 a1 = *(const short8*)&Vt[(64+l15)*LS + 32 + quad*8];
      c5 = __builtin_amdgcn_mfma_f32_16x16x32_bf16(a0, pf0, c5, 0,0,0);
      c5 = __builtin_amdgcn_mfma_f32_16x16x32_bf16(a1, pf1, c5, 0,0,0);
    }
  }

  if (SPLIT){
    float* Ar = Acc + (size_t)(bh*N_ + rt*64 + wv*16 + l15)*ASTR;
    #pragma unroll
    for (int s2=0;s2<4;++s2)
      #pragma unroll
      for (int i=0;i<4;++i)
        atomicAdd(&Ar[s2*16 + quad*4 + i], acc[s2][i]);
    if (quad == 0)
      atomicAdd(&Ar[64], c5[0]);
  } else {
    float rs_n = __shfl(c5[0], l15);    // D row 0 (quad0,reg0), col=query row
    float inv = 1.0f / fmaxf(rs_n, 1e-12f);
    float* Og = out + (size_t)bh*N_*D_ + (size_t)(rt*64 + wv*16 + l15)*D_;
    #pragma unroll
    for (int s2=0;s2<4;++s2)
      #pragma unroll
      for (int i=0;i<4;++i)
        Og[s2*16 + quad*4 + i] = acc[s2][i] * inv;
  }
}

// k4: out = Acc[:,0:64] / Acc[:,64]
__global__ __launch_bounds__(256) void k4_norm(const float* __restrict__ Acc,
                                               float* __restrict__ out){
  int idx = blockIdx.x*256 + threadIdx.x;     // 524288 float4s
  int n = idx >> 4, c4 = (idx & 15) << 2;
  const float* Ar = Acc + (size_t)n*ASTR;
  float4v v = *(const float4v*)(Ar + c4);
  float inv = 1.0f / fmaxf(Ar[64], 1e-12f);
  float4v o = {v.x*inv, v.y*inv, v.z*inv, v.w*inv};
  *(float4v*)(out + (size_t)n*64 + c4) = o;
}

// fallback pass2 (round-3, verified)
__global__ __launch_bounds__(256) void spop_pass2(
    const float* __restrict__ Q, const float* __restrict__ K,
    const float* __restrict__ V, const int* __restrict__ mask,
    const float* __restrict__ w, float* __restrict__ out)
{
  __shared__ unsigned short Khi[64*LS], Klo[64*LS];
  __shared__ unsigned short Vt[64*LS];
  __shared__ unsigned short Ps[64*LS];
  __shared__ float msk[64], wms[64];

  const int rt = blockIdx.x, bh = blockIdx.y, b = bh>>3;
  const int tid = threadIdx.x;
  const int wv = tid>>6, lane = tid&63, quad = lane>>4, l15 = lane&15;

  const float* Qg = Q + (size_t)bh*N_*D_;
  const float* Kg = K + (size_t)bh*N_*D_;
  const float* Vg = V + (size_t)bh*N_*D_;

  short8 qhi[2], qlo[2];
  {
    const float* qp = Qg + (size_t)(rt*64 + wv*16 + l15)*D_ + quad*8;
    load_split8(qp,      qhi[0], qlo[0]);
    load_split8(qp + 32, qhi[1], qlo[1]);
  }

  float4v acc[4];
  #pragma unroll
  for (int i=0;i<4;++i) acc[i] = (float4v){0.f,0.f,0.f,0.f};
  float rs = 0.f;

  for (int kt=0; kt<NT_; ++kt){
    __syncthreads();
    #pragma unroll
    for (int it=0; it<4; ++it){
      int idx = tid + it*256;
      int r = idx>>4, d4 = (idx&15)<<2;
      const float4v v = *(const float4v*)(Kg + (size_t)(kt*64 + r)*D_ + d4);
      unsigned h0,l0,h1,l1;
      split2(v.x, v.y, h0, l0);
      split2(v.z, v.w, h1, l1);
      unsigned* KhiW = (unsigned*)Khi; unsigned* KloW = (unsigned*)Klo;
      int base = r*LSW + (d4>>1);
      KhiW[base] = h0; KhiW[base+1] = h1;
      KloW[base] = l0; KloW[base+1] = l1;
    }
    #pragma unroll
    for (int it=0; it<2; ++it){
      int u = tid + it*256;
      int kp = u & 31;
      int d4 = (u>>5)<<2;
      const float* vp = Vg + (size_t)(kt*64 + kp*2)*D_ + d4;
      float4v a0 = *(const float4v*)vp;
      float4v a1 = *(const float4v*)(vp + D_);
      unsigned* VtW = (unsigned*)Vt;
      VtW[(d4+0)*LSW + kp] = packbf2(a0.x, a1.x);
      VtW[(d4+1)*LSW + kp] = packbf2(a0.y, a1.y);
      VtW[(d4+2)*LSW + kp] = packbf2(a0.z, a1.z);
      VtW[(d4+3)*LSW + kp] = packbf2(a0.w, a1.w);
    }
    if (tid < 64){
      int gk = kt*64 + tid;
      msk[tid] = (mask[b*N_ + gk] == 0) ? 1.f : 0.f;
      wms[tid] = w[bh*N_ + gk];
    }
    __syncthreads();

    #pragma unroll
    for (int s=0;s<4;++s){
      float4v c = {0.f,0.f,0.f,0.f};
      #pragma unroll
      for (int cc=0; cc<2; ++cc){
        const short8 ahi = *(const short8*)&Khi[(s*16+l15)*LS + cc*32 + quad*8];
        const short8 alo = *(const short8*)&Klo[(s*16+l15)*LS + cc*32 + quad*8];
        c = __builtin_amdgcn_mfma_f32_16x16x32_bf16(ahi, qhi[cc], c, 0,0,0);
        c = __builtin_amdgcn_mfma_f32_16x16x32_bf16(ahi, qlo[cc], c, 0,0,0);
        c = __builtin_amdgcn_mfma_f32_16x16x32_bf16(alo, qhi[cc], c, 0,0,0);
      }
      int kl = s*16 + quad*4;
      float sc0 = score_fn(c[0], msk[kl+0]) * wms[kl+0];
      float sc1 = score_fn(c[1], msk[kl+1]) * wms[kl+1];
      float sc2 = score_fn(c[2], msk[kl+2]) * wms[kl+2];
      float sc3 = score_fn(c[3], msk[kl+3]) * wms[kl+3];
      rs += (sc0 + sc1) + (sc2 + sc3);
      unsigned* PsW = (unsigned*)Ps;
      int pb = (wv*16 + l15)*LSW + (kl>>1);
      PsW[pb]   = packbf2(sc0, sc1);
      PsW[pb+1] = packbf2(sc2, sc3);
    }

    short8 pf[2];
    pf[0] = *(const short8*)&Ps[(wv*16+l15)*LS +  0 + quad*8];
    pf[1] = *(const short8*)&Ps[(wv*16+l15)*LS + 32 + quad*8];
    #pragma unroll
    for (int s2=0;s2<4;++s2){
      #pragma unroll
      for (int cc=0; cc<2; ++cc){
        const short8 av = *(const short8*)&Vt[(s2*16+l15)*LS + cc*32 + quad*8];
        acc[s2] = __builtin_amdgcn_mfma_f32_16x16x32_bf16(av, pf[cc], acc[s2], 0,0,0);
      }
    }
  }

  rs += __shfl_xor(rs, 16);
  rs += __shfl_xor(rs, 32);
  float inv = 1.0f / fmaxf(rs, 1e-12f);

  float* Og = out + (size_t)bh*N_*D_ + (size_t)(rt*64 + wv*16 + l15)*D_;
  #pragma unroll
  for (int s2=0;s2<4;++s2)
    #pragma unroll
    for (int i=0;i<4;++i)
      Og[s2*16 + quad*4 + i] = acc[s2][i] * inv;
}

extern "C" void kernel_launch(void* const* d_in, const int* in_sizes, int n_in,
                              void* d_out, int out_size, void* d_ws, size_t ws_size,
                              hipStream_t stream) {
  (void)in_sizes; (void)n_in; (void)out_size;
  const float* Q   = (const float*)d_in[0];
  const float* K   = (const float*)d_in[1];
  const float* V   = (const float*)d_in[2];
  const int*  mask = (const int*)d_in[3];
  float* out = (float*)d_out;

  const size_t S_bytes   = (size_t)2*BH_*N_*N_;                 // 128 MiB
  const size_t acc_bytes = (size_t)BH_*N_*ASTR*sizeof(float);   // ~8.9 MB
  const size_t acc_off   = 262144;
  const size_t s_off_split = acc_off + ((acc_bytes + 255) & ~(size_t)255);
  const size_t need_split  = s_off_split + S_bytes;
  const size_t need_mat    = 262144 + S_bytes;

  if (ws_size >= need_split){
    float* nc = (float*)d_ws;
    float* w  = (float*)((char*)d_ws + 131072);
    float* Acc = (float*)((char*)d_ws + acc_off);
    unsigned short* S = (unsigned short*)((char*)d_ws + s_off_split);
    hipMemsetAsync(nc, 0, (size_t)BH_*N_*sizeof(float), stream);
    hipMemsetAsync(Acc, 0, acc_bytes, stream);
    k1_score<true><<<dim3(NT_, BH_, 8), 256, 0, stream>>>(Q, K, mask, nc, S);
    k2_w<<<dim3(BH_*N_/256), 256, 0, stream>>>(nc, w);
    k3_pv<true><<<dim3(NT_, BH_, 4), 256, 0, stream>>>(V, S, w, Acc, out);
    k4_norm<<<dim3(BH_*N_*16/256), 256, 0, stream>>>(Acc, out);
  } else if (ws_size >= need_mat){
    float* nc = (float*)d_ws;
    float* w  = (float*)((char*)d_ws + 131072);
    unsigned short* S = (unsigned short*)((char*)d_ws + 262144);
    hipMemsetAsync(nc, 0, (size_t)BH_*N_*sizeof(float), stream);
    k1_score<true><<<dim3(NT_, BH_, 8), 256, 0, stream>>>(Q, K, mask, nc, S);
    k2_w<<<dim3(BH_*N_/256), 256, 0, stream>>>(nc, w);
    k3_pv<false><<<dim3(NT_, BH_, 1), 256, 0, stream>>>(V, S, w, nullptr, out);
  } else {
    float* w = (float*)d_ws;
    k1_score<false><<<dim3(NT_, BH_, 1), 256, 0, stream>>>(Q, K, mask, w, nullptr);
    spop_pass2<<<dim3(NT_, BH_), 256, 0, stream>>>(Q, K, V, mask, w, out);
  }
}

// Round 8
// 227.870 us; speedup vs baseline: 1.7920x; 1.7920x over previous
//
#include <hip/hip_runtime.h>
#include <hip/hip_bf16.h>
#include <math.h>

#define B_ 2
#define H_ 8
#define N_ 2048
#define D_ 64
#define BH_ 16
#define NT_ (N_/64)
#define LS 72
#define LSW (LS/2)

typedef __attribute__((ext_vector_type(8))) short short8;
typedef __attribute__((ext_vector_type(4))) float float4v;

__device__ __forceinline__ unsigned packbf2(float a, float b){
  __hip_bfloat162 h = __float22bfloat162_rn(make_float2(a, b));
  return *(unsigned*)&h;
}
__device__ __forceinline__ void split2(float a, float b, unsigned& hi, unsigned& lo){
  hi = packbf2(a, b);
  float ha = __uint_as_float(hi << 16);
  float hb = __uint_as_float(hi & 0xFFFF0000u);
  lo = packbf2(a - ha, b - hb);
}
__device__ __forceinline__ void load_split8(const float* p, short8& hi8, short8& lo8){
  float4v v0 = *(const float4v*)p;
  float4v v1 = *(const float4v*)(p + 4);
  unsigned h0,h1,h2,h3,l0,l1,l2,l3;
  split2(v0.x, v0.y, h0, l0);
  split2(v0.z, v0.w, h1, l1);
  split2(v1.x, v1.y, h2, l2);
  split2(v1.z, v1.w, h3, l3);
  unsigned ph[4] = {h0,h1,h2,h3};
  unsigned pl[4] = {l0,l1,l2,l3};
  hi8 = *(short8*)ph;
  lo8 = *(short8*)pl;
}
__device__ __forceinline__ float acos_poly(float z){
  float p = 4.2163199048e-2f;
  p = __builtin_fmaf(p, z, 2.4181311049e-2f);
  p = __builtin_fmaf(p, z, 4.5470025998e-2f);
  p = __builtin_fmaf(p, z, 7.4953002686e-2f);
  p = __builtin_fmaf(p, z, 1.6666752422e-1f);
  return p;
}
__device__ __forceinline__ float score_fn(float qk, float masked){
  const float LO = -1.0f + 1e-7f;
  const float HI =  1.0f - 1e-7f;
  float x  = fminf(fmaxf(qk, LO), HI);
  float ax = fabsf(x);
  bool big = ax > 0.5f;
  float z  = big ? (0.5f*(1.0f - ax)) : (x*x);
  float s  = big ? __builtin_amdgcn_sqrtf(z) : x;
  float p  = acos_poly(z);
  float r  = __builtin_fmaf(s*z, p, s);
  float g_big   = (x >= 0.0f) ? (2.0f*r) : __builtin_fmaf(-2.0f, r, 3.14159265358979f);
  float g_small = 1.57079632679490f - r;
  float g = big ? g_big : g_small;
  g = (masked != 0.0f) ? 10000.0f : g;
  float w1 = 1.0f + g;
  float w2 = w1*w1;
  float w4 = w2*w2;
  float w5 = w4*w1;
  return __builtin_amdgcn_rcpf(w5);
}

// k1 (STORE=true): scores -> S bf16, col sums atomically into ncw.
// k1 (STORE=false): full column sums, ncw = n_c^-0.5 directly (fallback pass1).
template<bool STORE>
__global__ __launch_bounds__(256) void k1_score(
    const float* __restrict__ Q, const float* __restrict__ K,
    const int* __restrict__ mask, float* __restrict__ ncw,
    unsigned short* __restrict__ S)
{
  __shared__ unsigned short Qhi[64*LS], Qlo[64*LS];
  __shared__ float msk[64];
  __shared__ float red[64*4];

  const int kt = blockIdx.x, bh = blockIdx.y, rz = blockIdx.z;
  const int nz = gridDim.z;
  const int tid = threadIdx.x;
  const int wv = tid>>6, lane = tid&63, quad = lane>>4, l15 = lane&15;

  const float* Qg = Q + (size_t)bh*N_*D_;
  const float* Kg = K + (size_t)bh*N_*D_;

  short8 khi[4][2], klo[4][2];
  #pragma unroll
  for (int s=0;s<4;++s){
    const float* kp = Kg + (size_t)(kt*64 + s*16 + l15)*D_ + quad*8;
    load_split8(kp,      khi[s][0], klo[s][0]);
    load_split8(kp + 32, khi[s][1], klo[s][1]);
  }
  if (tid < 64)
    msk[tid] = (mask[(bh>>3)*N_ + kt*64 + tid] == 0) ? 1.f : 0.f;

  float cs[4][4];
  #pragma unroll
  for (int s=0;s<4;++s)
    #pragma unroll
    for (int i=0;i<4;++i) cs[s][i] = 0.f;

  const int iters = NT_/nz;
  for (int rti=0; rti<iters; ++rti){
    const int rt = rz*iters + rti;
    __syncthreads();
    #pragma unroll
    for (int it=0; it<4; ++it){
      int idx = tid + it*256;
      int r = idx>>4, d4 = (idx&15)<<2;
      const float4v v = *(const float4v*)(Qg + (size_t)(rt*64 + r)*D_ + d4);
      unsigned h0,l0,h1,l1;
      split2(v.x, v.y, h0, l0);
      split2(v.z, v.w, h1, l1);
      unsigned* QhiW = (unsigned*)Qhi; unsigned* QloW = (unsigned*)Qlo;
      int base = r*LSW + (d4>>1);
      QhiW[base] = h0; QhiW[base+1] = h1;
      QloW[base] = l0; QloW[base+1] = l1;
    }
    __syncthreads();

    short8 bhi[2], blo[2];
    #pragma unroll
    for (int cc=0; cc<2; ++cc){
      bhi[cc] = *(const short8*)&Qhi[(wv*16+l15)*LS + cc*32 + quad*8];
      blo[cc] = *(const short8*)&Qlo[(wv*16+l15)*LS + cc*32 + quad*8];
    }
    const size_t nrow = (size_t)(bh*NT_ + kt)*N_ + (size_t)rt*64 + wv*16 + l15;
    #pragma unroll
    for (int s=0;s<4;++s){
      float4v c = {0.f,0.f,0.f,0.f};
      #pragma unroll
      for (int cc=0; cc<2; ++cc){
        c = __builtin_amdgcn_mfma_f32_16x16x32_bf16(khi[s][cc], bhi[cc], c, 0,0,0);
        c = __builtin_amdgcn_mfma_f32_16x16x32_bf16(khi[s][cc], blo[cc], c, 0,0,0);
        c = __builtin_amdgcn_mfma_f32_16x16x32_bf16(klo[s][cc], bhi[cc], c, 0,0,0);
      }
      int kl = s*16 + quad*4;
      float sc0 = score_fn(c[0], msk[kl+0]);
      float sc1 = score_fn(c[1], msk[kl+1]);
      float sc2 = score_fn(c[2], msk[kl+2]);
      float sc3 = score_fn(c[3], msk[kl+3]);
      cs[s][0]+=sc0; cs[s][1]+=sc1; cs[s][2]+=sc2; cs[s][3]+=sc3;
      if (STORE){
        uint2 pk;
        pk.x = packbf2(sc0, sc1);
        pk.y = packbf2(sc2, sc3);
        *(uint2*)&S[nrow*64 + kl] = pk;
      }
    }
  }

  #pragma unroll
  for (int s=0;s<4;++s)
    #pragma unroll
    for (int i=0;i<4;++i){
      float v2 = cs[s][i];
      v2 += __shfl_xor(v2, 1);
      v2 += __shfl_xor(v2, 2);
      v2 += __shfl_xor(v2, 4);
      v2 += __shfl_xor(v2, 8);
      cs[s][i] = v2;
    }
  if (l15 == 0){
    #pragma unroll
    for (int s=0;s<4;++s)
      #pragma unroll
      for (int i=0;i<4;++i)
        red[(s*16 + quad*4 + i)*4 + wv] = cs[s][i];
  }
  __syncthreads();
  if (tid < 64){
    float t = red[tid*4+0] + red[tid*4+1] + red[tid*4+2] + red[tid*4+3];
    if (STORE) atomicAdd(&ncw[bh*N_ + kt*64 + tid], t);
    else       ncw[bh*N_ + kt*64 + tid] = 1.0f / sqrtf(t);
  }
}

__global__ __launch_bounds__(256) void k2_w(const float* __restrict__ nc,
                                            float* __restrict__ w){
  int i = blockIdx.x*256 + threadIdx.x;
  w[i] = 1.0f / sqrtf(fmaxf(nc[i], 1e-30f));
}

// k3_big: 1024 threads = 4 wave-groups; group g covers key tiles g*8..g*8+7
// into register accumulators; in-LDS cross-group reduction at the end.
// No atomics, no extra workspace.
__global__ __launch_bounds__(1024) void k3_big(
    const float* __restrict__ V, const unsigned short* __restrict__ S,
    const float* __restrict__ w, float* __restrict__ out)
{
  __shared__ float smem_f[13056];   // 52224 B: 4 Vt slices (46080 B) / Red buffer

  const int rt = blockIdx.x, bh = blockIdx.y;
  const int tid = threadIdx.x;
  const int g   = tid >> 8;          // wave-group 0..3
  const int t2  = tid & 255;         // thread within group
  const int wv  = t2 >> 6;           // wave within group 0..3
  const int lane = tid & 63, quad = lane>>4, l15 = lane&15;

  const float* Vg = V + (size_t)bh*N_*D_;
  const float* wg = w + (size_t)bh*N_;

  unsigned short* Vt = (unsigned short*)smem_f + (size_t)g*80*LS;

  // zero rows 64..79 of this group's Vt slice (w row 64; rows 65..79 pad)
  {
    unsigned* VtW = (unsigned*)(Vt + (size_t)64*LS);
    for (int z = t2; z < 16*LSW; z += 256) VtW[z] = 0u;
  }

  float4v acc[4];
  #pragma unroll
  for (int i=0;i<4;++i) acc[i] = (float4v){0.f,0.f,0.f,0.f};
  float4v c5 = {0.f,0.f,0.f,0.f};

  for (int ki=0; ki<8; ++ki){
    const int kt = g*8 + ki;
    __syncthreads();
    // stage (w*V)^T into this group's Vt slice
    #pragma unroll
    for (int it=0; it<2; ++it){
      int u = t2 + it*256;
      int kp = u & 31;
      int d4 = (u>>5)<<2;
      int m0 = kt*64 + kp*2;
      float wa = wg[m0], wb = wg[m0+1];
      const float* vp = Vg + (size_t)m0*D_ + d4;
      float4v a0 = *(const float4v*)vp;
      float4v a1 = *(const float4v*)(vp + D_);
      unsigned* VtW = (unsigned*)Vt;
      VtW[(d4+0)*LSW + kp] = packbf2(a0.x*wa, a1.x*wb);
      VtW[(d4+1)*LSW + kp] = packbf2(a0.y*wa, a1.y*wb);
      VtW[(d4+2)*LSW + kp] = packbf2(a0.z*wa, a1.z*wb);
      VtW[(d4+3)*LSW + kp] = packbf2(a0.w*wa, a1.w*wb);
    }
    if (t2 < 32){
      int m0 = kt*64 + t2*2;
      ((unsigned*)Vt)[64*LSW + t2] = packbf2(wg[m0], wg[m0+1]);
    }
    __syncthreads();

    const size_t base = ((size_t)(bh*NT_ + kt)*N_ + (size_t)rt*64 + wv*16 + l15)*64;
    short8 pf0 = *(const short8*)&S[base +  0 + quad*8];
    short8 pf1 = *(const short8*)&S[base + 32 + quad*8];

    #pragma unroll
    for (int s2=0;s2<4;++s2){
      const short8 a0 = *(const short8*)&Vt[(s2*16+l15)*LS +  0 + quad*8];
      const short8 a1 = *(const short8*)&Vt[(s2*16+l15)*LS + 32 + quad*8];
      acc[s2] = __builtin_amdgcn_mfma_f32_16x16x32_bf16(a0, pf0, acc[s2], 0,0,0);
      acc[s2] = __builtin_amdgcn_mfma_f32_16x16x32_bf16(a1, pf1, acc[s2], 0,0,0);
    }
    {
      const short8 a0 = *(const short8*)&Vt[(64+l15)*LS +  0 + quad*8];
      const short8 a1 = *(const short8*)&Vt[(64+l15)*LS + 32 + quad*8];
      c5 = __builtin_amdgcn_mfma_f32_16x16x32_bf16(a0, pf0, c5, 0,0,0);
      c5 = __builtin_amdgcn_mfma_f32_16x16x32_bf16(a1, pf1, c5, 0,0,0);
    }
  }

  // cross-group reduction in LDS (Red aliases the Vt slices; stride 68 floats)
  __syncthreads();
  float* Red = smem_f;
  if (g > 0){
    float* Rr = Red + ((size_t)(g-1)*64 + (wv*16 + l15))*68;
    #pragma unroll
    for (int s2=0;s2<4;++s2)
      #pragma unroll
      for (int i=0;i<4;++i)
        Rr[s2*16 + quad*4 + i] = acc[s2][i];
    if (quad == 0) Rr[64] = c5[0];
  }
  __syncthreads();
  if (g == 0){
    const int row = wv*16 + l15;
    #pragma unroll
    for (int gg=0; gg<3; ++gg){
      const float* Rr = Red + ((size_t)gg*64 + row)*68;
      #pragma unroll
      for (int s2=0;s2<4;++s2)
        #pragma unroll
        for (int i=0;i<4;++i)
          acc[s2][i] += Rr[s2*16 + quad*4 + i];
    }
    float rs_n = __shfl(c5[0], l15);   // group-0 partial for this row
    #pragma unroll
    for (int gg=0; gg<3; ++gg)
      rs_n += Red[((size_t)gg*64 + row)*68 + 64];
    float inv = 1.0f / fmaxf(rs_n, 1e-12f);

    float* Og = out + (size_t)bh*N_*D_ + (size_t)(rt*64 + row)*D_;
    #pragma unroll
    for (int s2=0;s2<4;++s2)
      #pragma unroll
      for (int i=0;i<4;++i)
        Og[s2*16 + quad*4 + i] = acc[s2][i] * inv;
  }
}

// fallback pass2 (round-3, verified)
__global__ __launch_bounds__(256) void spop_pass2(
    const float* __restrict__ Q, const float* __restrict__ K,
    const float* __restrict__ V, const int* __restrict__ mask,
    const float* __restrict__ w, float* __restrict__ out)
{
  __shared__ unsigned short Khi[64*LS], Klo[64*LS];
  __shared__ unsigned short Vt[64*LS];
  __shared__ unsigned short Ps[64*LS];
  __shared__ float msk[64], wms[64];

  const int rt = blockIdx.x, bh = blockIdx.y, b = bh>>3;
  const int tid = threadIdx.x;
  const int wv = tid>>6, lane = tid&63, quad = lane>>4, l15 = lane&15;

  const float* Qg = Q + (size_t)bh*N_*D_;
  const float* Kg = K + (size_t)bh*N_*D_;
  const float* Vg = V + (size_t)bh*N_*D_;

  short8 qhi[2], qlo[2];
  {
    const float* qp = Qg + (size_t)(rt*64 + wv*16 + l15)*D_ + quad*8;
    load_split8(qp,      qhi[0], qlo[0]);
    load_split8(qp + 32, qhi[1], qlo[1]);
  }

  float4v acc[4];
  #pragma unroll
  for (int i=0;i<4;++i) acc[i] = (float4v){0.f,0.f,0.f,0.f};
  float rs = 0.f;

  for (int kt=0; kt<NT_; ++kt){
    __syncthreads();
    #pragma unroll
    for (int it=0; it<4; ++it){
      int idx = tid + it*256;
      int r = idx>>4, d4 = (idx&15)<<2;
      const float4v v = *(const float4v*)(Kg + (size_t)(kt*64 + r)*D_ + d4);
      unsigned h0,l0,h1,l1;
      split2(v.x, v.y, h0, l0);
      split2(v.z, v.w, h1, l1);
      unsigned* KhiW = (unsigned*)Khi; unsigned* KloW = (unsigned*)Klo;
      int base = r*LSW + (d4>>1);
      KhiW[base] = h0; KhiW[base+1] = h1;
      KloW[base] = l0; KloW[base+1] = l1;
    }
    #pragma unroll
    for (int it=0; it<2; ++it){
      int u = tid + it*256;
      int kp = u & 31;
      int d4 = (u>>5)<<2;
      const float* vp = Vg + (size_t)(kt*64 + kp*2)*D_ + d4;
      float4v a0 = *(const float4v*)vp;
      float4v a1 = *(const float4v*)(vp + D_);
      unsigned* VtW = (unsigned*)Vt;
      VtW[(d4+0)*LSW + kp] = packbf2(a0.x, a1.x);
      VtW[(d4+1)*LSW + kp] = packbf2(a0.y, a1.y);
      VtW[(d4+2)*LSW + kp] = packbf2(a0.z, a1.z);
      VtW[(d4+3)*LSW + kp] = packbf2(a0.w, a1.w);
    }
    if (tid < 64){
      int gk = kt*64 + tid;
      msk[tid] = (mask[b*N_ + gk] == 0) ? 1.f : 0.f;
      wms[tid] = w[bh*N_ + gk];
    }
    __syncthreads();

    #pragma unroll
    for (int s=0;s<4;++s){
      float4v c = {0.f,0.f,0.f,0.f};
      #pragma unroll
      for (int cc=0; cc<2; ++cc){
        const short8 ahi = *(const short8*)&Khi[(s*16+l15)*LS + cc*32 + quad*8];
        const short8 alo = *(const short8*)&Klo[(s*16+l15)*LS + cc*32 + quad*8];
        c = __builtin_amdgcn_mfma_f32_16x16x32_bf16(ahi, qhi[cc], c, 0,0,0);
        c = __builtin_amdgcn_mfma_f32_16x16x32_bf16(ahi, qlo[cc], c, 0,0,0);
        c = __builtin_amdgcn_mfma_f32_16x16x32_bf16(alo, qhi[cc], c, 0,0,0);
      }
      int kl = s*16 + quad*4;
      float sc0 = score_fn(c[0], msk[kl+0]) * wms[kl+0];
      float sc1 = score_fn(c[1], msk[kl+1]) * wms[kl+1];
      float sc2 = score_fn(c[2], msk[kl+2]) * wms[kl+2];
      float sc3 = score_fn(c[3], msk[kl+3]) * wms[kl+3];
      rs += (sc0 + sc1) + (sc2 + sc3);
      unsigned* PsW = (unsigned*)Ps;
      int pb = (wv*16 + l15)*LSW + (kl>>1);
      PsW[pb]   = packbf2(sc0, sc1);
      PsW[pb+1] = packbf2(sc2, sc3);
    }

    short8 pf[2];
    pf[0] = *(const short8*)&Ps[(wv*16+l15)*LS +  0 + quad*8];
    pf[1] = *(const short8*)&Ps[(wv*16+l15)*LS + 32 + quad*8];
    #pragma unroll
    for (int s2=0;s2<4;++s2){
      #pragma unroll
      for (int cc=0; cc<2; ++cc){
        const short8 av = *(const short8*)&Vt[(s2*16+l15)*LS + cc*32 + quad*8];
        acc[s2] = __builtin_amdgcn_mfma_f32_16x16x32_bf16(av, pf[cc], acc[s2], 0,0,0);
      }
    }
  }

  rs += __shfl_xor(rs, 16);
  rs += __shfl_xor(rs, 32);
  float inv = 1.0f / fmaxf(rs, 1e-12f);

  float* Og = out + (size_t)bh*N_*D_ + (size_t)(rt*64 + wv*16 + l15)*D_;
  #pragma unroll
  for (int s2=0;s2<4;++s2)
    #pragma unroll
    for (int i=0;i<4;++i)
      Og[s2*16 + quad*4 + i] = acc[s2][i] * inv;
}

extern "C" void kernel_launch(void* const* d_in, const int* in_sizes, int n_in,
                              void* d_out, int out_size, void* d_ws, size_t ws_size,
                              hipStream_t stream) {
  (void)in_sizes; (void)n_in; (void)out_size;
  const float* Q   = (const float*)d_in[0];
  const float* K   = (const float*)d_in[1];
  const float* V   = (const float*)d_in[2];
  const int*  mask = (const int*)d_in[3];
  float* out = (float*)d_out;

  const size_t S_bytes  = (size_t)2*BH_*N_*N_;   // 128 MiB
  const size_t need_mat = 262144 + S_bytes;

  if (ws_size >= need_mat){
    float* nc = (float*)d_ws;
    float* w  = (float*)((char*)d_ws + 131072);
    unsigned short* S = (unsigned short*)((char*)d_ws + 262144);
    hipMemsetAsync(nc, 0, (size_t)BH_*N_*sizeof(float), stream);
    k1_score<true><<<dim3(NT_, BH_, 4), 256, 0, stream>>>(Q, K, mask, nc, S);
    k2_w<<<dim3(BH_*N_/256), 256, 0, stream>>>(nc, w);
    k3_big<<<dim3(NT_, BH_), 1024, 0, stream>>>(V, S, w, out);
  } else {
    float* w = (float*)d_ws;
    k1_score<false><<<dim3(NT_, BH_, 1), 256, 0, stream>>>(Q, K, mask, w, nullptr);
    spop_pass2<<<dim3(NT_, BH_), 256, 0, stream>>>(Q, K, V, mask, w, out);
  }
}